// Round 1
// baseline (897.337 us; speedup 1.0000x reference)
//
#include <hip/hip_runtime.h>
#include <hip/hip_bf16.h>
#include <math.h>

#define NEG_SLOPE 0.2f

typedef unsigned short ushortT;
typedef __attribute__((ext_vector_type(8))) short short8;   // 8 bf16 = 4 VGPRs (MFMA A/B frag)
typedef __attribute__((ext_vector_type(4))) float f32x4;    // MFMA C/D frag

static __device__ __forceinline__ float leaky(float x){ return x > 0.f ? x : NEG_SLOPE * x; }
static __device__ __forceinline__ float elu(float x){ return x > 0.f ? x : (__expf(x) - 1.f); }

// bf16 helpers: RNE pack, exact unpack
static __device__ __forceinline__ ushortT f2bf(float f){
  unsigned u = __float_as_uint(f);
  u += 0x7fff + ((u >> 16) & 1);
  return (ushortT)(u >> 16);
}
static __device__ __forceinline__ float bf2f(ushortT h){ return __uint_as_float((unsigned)h << 16); }
static __device__ __forceinline__ float bf_lo(unsigned u){ return __uint_as_float(u << 16); }
static __device__ __forceinline__ float bf_hi(unsigned u){ return __uint_as_float(u & 0xffff0000u); }

// A-plane layout: elem (row,k) -> [ (k/32)*Mpad + row ]*32 + k%32
//   (GEMM frag-loadable AND 64B-line-contiguous for agg stores — zero RMW)
// B-plane layout: [(ntile*8 + t)*64 + lane]*8 (contiguous 1KB per wave frag)

// ---------------- edge sort by dst (counting sort) ----------------
__global__ void hist_kernel(const int* __restrict__ dst, int E, int* __restrict__ counts){
  int i = blockIdx.x*blockDim.x + threadIdx.x;
  if(i < E) atomicAdd(&counts[dst[i]], 1);
}

__global__ void scan1_kernel(const int* __restrict__ counts, int N,
                             int* __restrict__ offsets, int* __restrict__ blocksums){
  __shared__ int sdata[1024];
  int i = blockIdx.x*1024 + threadIdx.x;
  int v = (i<N) ? counts[i] : 0;
  sdata[threadIdx.x] = v;
  __syncthreads();
  for(int off=1; off<1024; off<<=1){
    int t = (threadIdx.x >= off) ? sdata[threadIdx.x-off] : 0;
    __syncthreads();
    sdata[threadIdx.x] += t;
    __syncthreads();
  }
  if(i<N) offsets[i] = sdata[threadIdx.x] - v;
  if(threadIdx.x==1023) blocksums[blockIdx.x] = sdata[1023];
}

__global__ void scan2_kernel(int* __restrict__ blocksums, int nb){
  __shared__ int sdata[64];
  int v = ((int)threadIdx.x < nb) ? blocksums[threadIdx.x] : 0;
  sdata[threadIdx.x] = v;
  __syncthreads();
  for(int off=1; off<64; off<<=1){
    int t = (threadIdx.x >= off) ? sdata[threadIdx.x-off] : 0;
    __syncthreads();
    sdata[threadIdx.x] += t;
    __syncthreads();
  }
  if((int)threadIdx.x < nb) blocksums[threadIdx.x] = sdata[threadIdx.x] - v;
}

__global__ void scan3_kernel(int* __restrict__ offsets, const int* __restrict__ blocksums,
                             int N, int E, int* __restrict__ cursor){
  int i = blockIdx.x*1024 + threadIdx.x;
  if(i < N){
    int o = offsets[i] + blocksums[blockIdx.x];
    offsets[i] = o;
    cursor[i] = o;
  }
  if(i == 0) offsets[N] = E;
}

__global__ void scatter_kernel(const int* __restrict__ src, const int* __restrict__ dst, int E,
                               int* __restrict__ cursor, int* __restrict__ ssrc,
                               int* __restrict__ sdst){
  int i = blockIdx.x*blockDim.x + threadIdx.x;
  if(i < E){
    int d = dst[i];
    int p = atomicAdd(&cursor[d], 1);
    ssrc[p] = src[i];
    sdst[p] = d;
  }
}

// ---------------- W split to packed fragment order: W[K=256, N] -> packed[16 ntiles] ----------------
__global__ __launch_bounds__(256) void wsplit_pack(const float* __restrict__ W, int N,
                              ushortT* __restrict__ Wh, ushortT* __restrict__ Wl){
  int idx = blockIdx.x*256 + threadIdx.x;     // < 16*8*64 = 8192
  int lane = idx & 63;
  int t  = (idx >> 6) & 7;
  int nt = idx >> 9;
  int l15 = lane & 15, quad = lane >> 4;
  int n = nt*16 + l15;
  ushortT h[8], l[8];
  #pragma unroll
  for(int j=0;j<8;j++){
    int k = t*32 + quad*8 + j;
    float v = (n < N) ? W[(size_t)k*N + n] : 0.f;
    h[j] = f2bf(v);
    l[j] = f2bf(v - bf2f(h[j]));
  }
  *(short8*)&Wh[(size_t)idx*8] = *(short8*)h;
  *(short8*)&Wl[(size_t)idx*8] = *(short8*)l;
}

// ---------------- x split fp32 [M][256] -> A-plane layout [t][Mpad][32] ----------------
__global__ __launch_bounds__(256) void xsplit_pack(const float* __restrict__ x, int M, int Mpad,
                              ushortT* __restrict__ Xh, ushortT* __restrict__ Xl){
  int idx = blockIdx.x*256 + threadIdx.x;     // over 8*Mpad, idx = t*Mpad + m
  if(idx >= 8*Mpad) return;
  int t = idx / Mpad, m = idx - t*Mpad;
  size_t base = (size_t)idx * 32;
  if(m < M){
    const float* xr = &x[(size_t)m*256 + t*32];
    #pragma unroll
    for(int c=0;c<4;c++){
      float4 v0 = *(const float4*)&xr[c*8];
      float4 v1 = *(const float4*)&xr[c*8+4];
      float vv[8] = {v0.x,v0.y,v0.z,v0.w,v1.x,v1.y,v1.z,v1.w};
      ushortT h[8], l[8];
      #pragma unroll
      for(int j=0;j<8;j++){
        h[j] = f2bf(vv[j]);
        l[j] = f2bf(vv[j] - bf2f(h[j]));
      }
      *(short8*)&Xh[base + c*8] = *(short8*)h;
      *(short8*)&Xl[base + c*8] = *(short8*)l;
    }
  } else {
    short8 z = {0,0,0,0,0,0,0,0};
    #pragma unroll
    for(int c=0;c<4;c++){ *(short8*)&Xh[base + c*8] = z; *(short8*)&Xl[base + c*8] = z; }
  }
}

// ---------------- bf16x3 MFMA GEMM, A read ONCE: block = 32 rows x full 256 cols ----------------
__global__ __launch_bounds__(256) void gemm_packed(
    const ushortT* __restrict__ Ah, const ushortT* __restrict__ Al,
    const ushortT* __restrict__ Bh, const ushortT* __restrict__ Bl,
    ushortT* __restrict__ Cm, int M, int Mpad, int N,
    const float* __restrict__ al, const float* __restrict__ ar,
    float* __restrict__ el, float* __restrict__ er){
  const int lane = threadIdx.x & 63;
  const int wv   = threadIdx.x >> 6;
  const int l15  = lane & 15, quad = lane >> 4;
  const int m0   = blockIdx.x*32;
  const int n0   = wv*64;
  const int nt0  = n0 >> 4;     // 4 ntiles per wave

  f32x4 acc[2][4];
  #pragma unroll
  for(int i=0;i<2;i++)
    #pragma unroll
    for(int j=0;j<4;j++){ acc[i][j][0]=0.f; acc[i][j][1]=0.f; acc[i][j][2]=0.f; acc[i][j][3]=0.f; }

  #pragma unroll
  for(int t=0; t<8; t++){
    short8 a_h[2], a_l[2], b_h[4], b_l[4];
    #pragma unroll
    for(int i=0;i<2;i++){
      size_t ad = ((size_t)t*Mpad + (m0 + i*16 + l15))*32 + quad*8;
      a_h[i] = *(const short8*)&Ah[ad];
      a_l[i] = *(const short8*)&Al[ad];
    }
    #pragma unroll
    for(int j=0;j<4;j++){
      size_t bd = (((size_t)(nt0+j)*8 + t)*64 + lane)*8;
      b_h[j] = *(const short8*)&Bh[bd];
      b_l[j] = *(const short8*)&Bl[bd];
    }
    #pragma unroll
    for(int i=0;i<2;i++)
      #pragma unroll
      for(int j=0;j<4;j++){
        acc[i][j] = __builtin_amdgcn_mfma_f32_16x16x32_bf16(a_h[i], b_h[j], acc[i][j], 0,0,0);
        acc[i][j] = __builtin_amdgcn_mfma_f32_16x16x32_bf16(a_h[i], b_l[j], acc[i][j], 0,0,0);
        acc[i][j] = __builtin_amdgcn_mfma_f32_16x16x32_bf16(a_l[i], b_h[j], acc[i][j], 0,0,0);
      }
  }

  // fused el/er (layers 0/1): this wave's col-tile is exactly head wv
  if(al){
    const int h = wv;
    float alv[4], arv[4];
    #pragma unroll
    for(int j=0;j<4;j++){
      alv[j] = al[h*64 + j*16 + l15];
      arv[j] = ar[h*64 + j*16 + l15];
    }
    #pragma unroll
    for(int i=0;i<2;i++){
      #pragma unroll
      for(int r=0;r<4;r++){
        float pl = acc[i][0][r]*alv[0] + acc[i][1][r]*alv[1]
                 + acc[i][2][r]*alv[2] + acc[i][3][r]*alv[3];
        float pr = acc[i][0][r]*arv[0] + acc[i][1][r]*arv[1]
                 + acc[i][2][r]*arv[2] + acc[i][3][r]*arv[3];
        #pragma unroll
        for(int off=1; off<16; off<<=1){ pl += __shfl_xor(pl,off); pr += __shfl_xor(pr,off); }
        int gm = m0 + i*16 + quad*4 + r;
        if(l15==0 && gm < M){ el[gm*4+h] = pl; er[gm*4+h] = pr; }
      }
    }
  }

  // C store, row-major bf16.  C/D layout: col=lane&15, row=quad*4+r
  #pragma unroll
  for(int i=0;i<2;i++){
    #pragma unroll
    for(int r=0;r<4;r++){
      int gm = m0 + i*16 + quad*4 + r;
      if(gm >= M) continue;
      #pragma unroll
      for(int j=0;j<4;j++){
        int gn = n0 + j*16 + l15;
        if(gn < N) Cm[(size_t)gm*N + gn] = f2bf(acc[i][j][r]);
      }
    }
  }
}

// ---------------- el/er projection from bf16 feat (layer 2 only) ----------------
__global__ void attn_proj_bf(const __hip_bfloat16* __restrict__ feat, const float* __restrict__ a_l,
                             const float* __restrict__ a_r, float* __restrict__ el,
                             float* __restrict__ er, int D){
  int n = blockIdx.x;
  int h = threadIdx.x >> 6;
  int lane = threadIdx.x & 63;
  float vl = 0.f, vr = 0.f;
  for(int d=lane; d<D; d+=64){
    float f = (float)feat[(size_t)n*4*D + h*D + d];
    vl = fmaf(f, a_l[h*D+d], vl);
    vr = fmaf(f, a_r[h*D+d], vr);
  }
  #pragma unroll
  for(int off=32; off; off>>=1){ vl += __shfl_down(vl,off); vr += __shfl_down(vr,off); }
  if(lane==0){ el[n*4+h] = vl; er[n*4+h] = vr; }
}

// ---------------- per-edge softmax numerators, HEAD-MAJOR planes ewp[h][e] ----------------
__global__ __launch_bounds__(256) void edge_w_kernel(const int* __restrict__ ssrc,
                              const int* __restrict__ sdst, int E,
                              const float4* __restrict__ el4, const float4* __restrict__ er4,
                              float* __restrict__ ewp){
  int e = blockIdx.x*blockDim.x + threadIdx.x;
  if(e >= E) return;
  int s = ssrc[e], d = sdst[e];
  float4 l = el4[s], r = er4[d];
  ewp[e]              = __expf(leaky(l.x + r.x));
  ewp[(size_t)E + e]  = __expf(leaky(l.y + r.y));
  ewp[(size_t)2*E + e]= __expf(leaky(l.z + r.z));
  ewp[(size_t)3*E + e]= __expf(leaky(l.w + r.w));
}

// ---------------- softmax + aggregate, layers 0/1: DIM-CHUNKED for XCD-L2 affinity ----------------
// chunk = blockIdx.x & 7 -> (round-robin dispatch) all blocks of chunk c land on XCD c.
// Chunk c covers dims [c*32, c*32+32) = one 64B line of the feature row AND one t-plane
// of the A-layout output -> per-XCD L2 working set = N*64B = 3.2MB < 4MB: gather becomes L2-hit.
// Wave = one dst node: 8 lanes per edge (dl), 8 edges in flight (eg); shuffle-reduce at end.
// Edge streams (ssrc, w-plane) + output stores use non-temporal hints to protect the slice.
__global__ __launch_bounds__(256) void agg_chunk_kernel(const uint2* __restrict__ feat2,
                           const float* __restrict__ ewp,
                           const int* __restrict__ offsets, const int* __restrict__ ssrc,
                           const float* __restrict__ bias,
                           ushortT* __restrict__ Hh, ushortT* __restrict__ Hl,
                           int N, int Mpad, int E){
  const int c   = blockIdx.x & 7;          // chunk = t-plane index
  const int nb  = blockIdx.x >> 3;
  const int wv  = threadIdx.x >> 6;
  const int lane= threadIdx.x & 63;
  const int n = nb*4 + wv;
  if(n >= N) return;
  const int dl = lane & 7;      // dim-lane: owns dims k = c*32 + dl*4 .. +3 (one uint2)
  const int eg = lane >> 3;     // edge slot 0..7
  const float* __restrict__ wh = ewp + (size_t)(c >> 1) * E;   // head = c/2
  const uint2* __restrict__ fc = feat2 + c*8 + dl;
  int e0 = offsets[n], e1 = offsets[n+1];
  float4 acc = make_float4(0.f,0.f,0.f,0.f);
  float den = 0.f;
  for(int e = e0 + eg; e < e1; e += 8){
    int s   = __builtin_nontemporal_load(&ssrc[e]);
    float w = __builtin_nontemporal_load(&wh[e]);
    uint2 q = fc[(size_t)s*64];
    acc.x = fmaf(w, bf_lo(q.x), acc.x);
    acc.y = fmaf(w, bf_hi(q.x), acc.y);
    acc.z = fmaf(w, bf_lo(q.y), acc.z);
    acc.w = fmaf(w, bf_hi(q.y), acc.w);
    den += w;
  }
  // reduce over the 8 edge slots: lanes {dl, dl+8, ..., dl+56}
  #pragma unroll
  for(int off=8; off<64; off<<=1){
    acc.x += __shfl_xor(acc.x, off);
    acc.y += __shfl_xor(acc.y, off);
    acc.z += __shfl_xor(acc.z, off);
    acc.w += __shfl_xor(acc.w, off);
    den   += __shfl_xor(den, off);
  }
  if(eg == 0){
    float inv = 1.f / fmaxf(den, 1e-9f);
    int k = c*32 + dl*4;
    float4 b4 = *(const float4*)&bias[k];
    float o0 = elu(acc.x*inv + b4.x);
    float o1 = elu(acc.y*inv + b4.y);
    float o2 = elu(acc.z*inv + b4.z);
    float o3 = elu(acc.w*inv + b4.w);
    ushortT h0=f2bf(o0), h1=f2bf(o1), h2=f2bf(o2), h3=f2bf(o3);
    ushort4 hv = make_ushort4(h0,h1,h2,h3);
    ushort4 lv = make_ushort4(f2bf(o0-bf2f(h0)), f2bf(o1-bf2f(h1)),
                              f2bf(o2-bf2f(h2)), f2bf(o3-bf2f(h3)));
    // A-plane store: 64B line (c*Mpad + n)*32, this lane's 8B at dl*4
    size_t ad = ((size_t)c*Mpad + n)*32 + (size_t)dl*4;
    __builtin_nontemporal_store(*(unsigned long long*)&hv, (unsigned long long*)&Hh[ad]);
    __builtin_nontemporal_store(*(unsigned long long*)&lv, (unsigned long long*)&Hl[ad]);
  }
}

// ---------------- layer 2: aggregate (H*C=160 bf16) + head-mean logits ----------------
__global__ __launch_bounds__(256) void agg2_kernel(const uint2* __restrict__ feat2,
                            const float* __restrict__ ewp,
                            const int* __restrict__ offsets, const int* __restrict__ ssrc,
                            const float* __restrict__ bias, float* __restrict__ logits,
                            int N, int E){
  __shared__ float s_out[4][160];
  int wv = threadIdx.x >> 6;
  int lane = threadIdx.x & 63;
  int n = blockIdx.x*4 + wv;
  bool valid = (n < N);
  if(valid && lane < 40){
    int h = lane / 10;
    const float* __restrict__ wh = ewp + (size_t)h * E;
    int e0 = offsets[n], e1 = offsets[n+1];
    float4 acc0 = make_float4(0.f,0.f,0.f,0.f), acc1 = acc0, acc2 = acc0, acc3 = acc0;
    float den0 = 0.f, den1 = 0.f, den2 = 0.f, den3 = 0.f;
    int e = e0;
    for(; e+3 < e1; e += 4){
      int s0 = ssrc[e], s1 = ssrc[e+1], s2 = ssrc[e+2], s3 = ssrc[e+3];
      float w0 = wh[e];
      float w1 = wh[e+1];
      float w2 = wh[e+2];
      float w3 = wh[e+3];
      uint2 q0 = feat2[(size_t)s0*40 + lane];
      uint2 q1 = feat2[(size_t)s1*40 + lane];
      uint2 q2 = feat2[(size_t)s2*40 + lane];
      uint2 q3 = feat2[(size_t)s3*40 + lane];
      acc0.x = fmaf(w0,bf_lo(q0.x),acc0.x); acc0.y = fmaf(w0,bf_hi(q0.x),acc0.y);
      acc0.z = fmaf(w0,bf_lo(q0.y),acc0.z); acc0.w = fmaf(w0,bf_hi(q0.y),acc0.w); den0 += w0;
      acc1.x = fmaf(w1,bf_lo(q1.x),acc1.x); acc1.y = fmaf(w1,bf_hi(q1.x),acc1.y);
      acc1.z = fmaf(w1,bf_lo(q1.y),acc1.z); acc1.w = fmaf(w1,bf_hi(q1.y),acc1.w); den1 += w1;
      acc2.x = fmaf(w2,bf_lo(q2.x),acc2.x); acc2.y = fmaf(w2,bf_hi(q2.x),acc2.y);
      acc2.z = fmaf(w2,bf_lo(q2.y),acc2.z); acc2.w = fmaf(w2,bf_hi(q2.y),acc2.w); den2 += w2;
      acc3.x = fmaf(w3,bf_lo(q3.x),acc3.x); acc3.y = fmaf(w3,bf_hi(q3.x),acc3.y);
      acc3.z = fmaf(w3,bf_lo(q3.y),acc3.z); acc3.w = fmaf(w3,bf_hi(q3.y),acc3.w); den3 += w3;
    }
    for(; e < e1; e++){
      int s = ssrc[e];
      float w = wh[e];
      uint2 q = feat2[(size_t)s*40 + lane];
      acc0.x = fmaf(w,bf_lo(q.x),acc0.x); acc0.y = fmaf(w,bf_hi(q.x),acc0.y);
      acc0.z = fmaf(w,bf_lo(q.y),acc0.z); acc0.w = fmaf(w,bf_hi(q.y),acc0.w); den0 += w;
    }
    float denom = (den0+den1) + (den2+den3);
    float4 acc;
    acc.x = (acc0.x+acc1.x) + (acc2.x+acc3.x);
    acc.y = (acc0.y+acc1.y) + (acc2.y+acc3.y);
    acc.z = (acc0.z+acc1.z) + (acc2.z+acc3.z);
    acc.w = (acc0.w+acc1.w) + (acc2.w+acc3.w);
    float inv = 1.f / fmaxf(denom, 1e-9f);
    float4 b4 = *(const float4*)&bias[lane*4];
    s_out[wv][lane*4+0] = acc.x*inv + b4.x;
    s_out[wv][lane*4+1] = acc.y*inv + b4.y;
    s_out[wv][lane*4+2] = acc.z*inv + b4.z;
    s_out[wv][lane*4+3] = acc.w*inv + b4.w;
  }
  __syncthreads();
  if(valid && lane < 40){
    logits[(size_t)n*40 + lane] =
        0.25f * (s_out[wv][lane] + s_out[wv][40+lane] + s_out[wv][80+lane] + s_out[wv][120+lane]);
  }
}

extern "C" void kernel_launch(void* const* d_in, const int* in_sizes, int n_in,
                              void* d_out, int out_size, void* d_ws, size_t ws_size,
                              hipStream_t stream){
  const float* x   = (const float*)d_in[0];
  const int*   eix = (const int*)  d_in[1];
  const float* W0  = (const float*)d_in[2];
  const float* al0 = (const float*)d_in[3];
  const float* ar0 = (const float*)d_in[4];
  const float* b0  = (const float*)d_in[5];
  const float* W1  = (const float*)d_in[6];
  const float* al1 = (const float*)d_in[7];
  const float* ar1 = (const float*)d_in[8];
  const float* b1  = (const float*)d_in[9];
  const float* W2  = (const float*)d_in[10];
  const float* al2 = (const float*)d_in[11];
  const float* ar2 = (const float*)d_in[12];
  const float* b2  = (const float*)d_in[13];
  float* logits = (float*)d_out;

  const int N = in_sizes[0] / 256;   // 50000
  const int E = in_sizes[1] / 2;     // 800000
  const int* src = eix;
  const int* dst = eix + E;
  const int nb = (N + 1023) / 1024;

  char* ws = (char*)d_ws;
  auto alloc = [&](size_t bytes)->char*{
    char* p = ws; ws += (bytes + 255) & ~(size_t)255; return p;
  };
  const int nblocksM = (N + 127)/128;
  const int Mpad = nblocksM * 128;
  const size_t apackElems = (size_t)Mpad * 256;
  int*   counts    = (int*)  alloc((size_t)N*4);
  int*   offsets   = (int*)  alloc((size_t)(N+1)*4);
  int*   cursor    = (int*)  alloc((size_t)N*4);
  int*   blocksums = (int*)  alloc((size_t)nb*4);
  int*   ssrc      = (int*)  alloc((size_t)E*4);
  int*   sdst      = (int*)  alloc((size_t)E*4);
  float* ew        = (float*)alloc((size_t)E*4*4);                  // 4 head-major planes [4][E]
  __hip_bfloat16* bufF = (__hip_bfloat16*)alloc((size_t)N*256*2);   // gemm output (bf16, row-major)
  ushortT* Hh      = (ushortT*)alloc(apackElems*2);                  // A hi plane [t][Mpad][32]
  ushortT* Hl      = (ushortT*)alloc(apackElems*2);                  // A lo plane
  float* el_buf    = (float*)alloc((size_t)N*4*4);
  float* er_buf    = (float*)alloc((size_t)N*4*4);
  ushortT* Wph0 = (ushortT*)alloc(16*8*64*8*2);
  ushortT* Wpl0 = (ushortT*)alloc(16*8*64*8*2);
  ushortT* Wph1 = (ushortT*)alloc(16*8*64*8*2);
  ushortT* Wpl1 = (ushortT*)alloc(16*8*64*8*2);
  ushortT* Wph2 = (ushortT*)alloc(16*8*64*8*2);
  ushortT* Wpl2 = (ushortT*)alloc(16*8*64*8*2);

  // sort edges by dst (graph fixed across layers — one sort per call)
  hipMemsetAsync(counts, 0, (size_t)N*4, stream);
  hist_kernel   <<<(E+255)/256, 256, 0, stream>>>(dst, E, counts);
  scan1_kernel  <<<nb, 1024, 0, stream>>>(counts, N, offsets, blocksums);
  scan2_kernel  <<<1, 64, 0, stream>>>(blocksums, nb);
  scan3_kernel  <<<nb, 1024, 0, stream>>>(offsets, blocksums, N, E, cursor);
  scatter_kernel<<<(E+255)/256, 256, 0, stream>>>(src, dst, E, cursor, ssrc, sdst);

  // weight + x packing (fragment order, hi/lo split)
  wsplit_pack<<<32, 256, 0, stream>>>(W0, 256, Wph0, Wpl0);
  wsplit_pack<<<32, 256, 0, stream>>>(W1, 256, Wph1, Wpl1);
  wsplit_pack<<<32, 256, 0, stream>>>(W2, 160, Wph2, Wpl2);
  int xtotal = 8 * Mpad;
  xsplit_pack<<<(xtotal+255)/256, 256, 0, stream>>>(x, N, Mpad, Hh, Hl);

  int ggBlocks = Mpad / 32;        // block = 32 rows x full-N; A read exactly once
  int aggGrid  = (N+3)/4;
  int aggChunkGrid = 8 * aggGrid;  // chunk = blockIdx & 7 -> XCD affinity
  int ewGrid  = (E+255)/256;
  // layer 0 (el/er fused in gemm epilogue)
  gemm_packed<<<ggBlocks, 256, 0, stream>>>(Hh, Hl, Wph0, Wpl0, (ushortT*)bufF, N, Mpad, 256, al0, ar0, el_buf, er_buf);
  edge_w_kernel<<<ewGrid, 256, 0, stream>>>(ssrc, sdst, E, (const float4*)el_buf, (const float4*)er_buf, ew);
  agg_chunk_kernel<<<aggChunkGrid, 256, 0, stream>>>((const uint2*)bufF, ew, offsets, ssrc, b0, Hh, Hl, N, Mpad, E);
  // layer 1
  gemm_packed<<<ggBlocks, 256, 0, stream>>>(Hh, Hl, Wph1, Wpl1, (ushortT*)bufF, N, Mpad, 256, al1, ar1, el_buf, er_buf);
  edge_w_kernel<<<ewGrid, 256, 0, stream>>>(ssrc, sdst, E, (const float4*)el_buf, (const float4*)er_buf, ew);
  agg_chunk_kernel<<<aggChunkGrid, 256, 0, stream>>>((const uint2*)bufF, ew, offsets, ssrc, b1, Hh, Hl, N, Mpad, E);
  // layer 2 (N=160: waves 2/3 partially idle on zero-padded B cols; stores guarded)
  gemm_packed<<<ggBlocks, 256, 0, stream>>>(Hh, Hl, Wph2, Wpl2, (ushortT*)bufF, N, Mpad, 160, nullptr, nullptr, nullptr, nullptr);
  attn_proj_bf<<<N, 256, 0, stream>>>(bufF, al2, ar2, el_buf, er_buf, 40);
  edge_w_kernel<<<ewGrid, 256, 0, stream>>>(ssrc, sdst, E, (const float4*)el_buf, (const float4*)er_buf, ew);
  agg2_kernel<<<aggGrid, 256, 0, stream>>>((const uint2*)bufF, ew, offsets, ssrc, b2, logits, N, E);
}

// Round 2
// 566.789 us; speedup vs baseline: 1.5832x; 1.5832x over previous
//
#include <hip/hip_runtime.h>
#include <hip/hip_bf16.h>
#include <math.h>

#define NEG_SLOPE 0.2f

typedef unsigned short ushortT;
typedef __attribute__((ext_vector_type(8))) short short8;   // 8 bf16 = 4 VGPRs (MFMA A/B frag)
typedef __attribute__((ext_vector_type(4))) float f32x4;    // MFMA C/D frag
typedef __attribute__((ext_vector_type(4), aligned(4))) int   int4u;   // 4B-aligned int4 load
typedef __attribute__((ext_vector_type(4), aligned(4))) float f4u;     // 4B-aligned float4 load

static __device__ __forceinline__ float leaky(float x){ return x > 0.f ? x : NEG_SLOPE * x; }
static __device__ __forceinline__ float elu(float x){ return x > 0.f ? x : (__expf(x) - 1.f); }

// bf16 helpers: RNE pack, exact unpack
static __device__ __forceinline__ ushortT f2bf(float f){
  unsigned u = __float_as_uint(f);
  u += 0x7fff + ((u >> 16) & 1);
  return (ushortT)(u >> 16);
}
static __device__ __forceinline__ float bf2f(ushortT h){ return __uint_as_float((unsigned)h << 16); }
static __device__ __forceinline__ float bf_lo(unsigned u){ return __uint_as_float(u << 16); }
static __device__ __forceinline__ float bf_hi(unsigned u){ return __uint_as_float(u & 0xffff0000u); }

// A-plane layout: elem (row,k) -> [ (k/32)*Mpad + row ]*32 + k%32
//   (GEMM frag-loadable AND 64B-line-contiguous for agg stores — zero RMW)
// B-plane layout: [(ntile*8 + t)*64 + lane]*8 (contiguous 1KB per wave frag)

// ---------------- edge sort by dst (counting sort) ----------------
__global__ void hist_kernel(const int* __restrict__ dst, int E, int* __restrict__ counts){
  int i = blockIdx.x*blockDim.x + threadIdx.x;
  if(i < E) atomicAdd(&counts[dst[i]], 1);
}

__global__ void scan1_kernel(const int* __restrict__ counts, int N,
                             int* __restrict__ offsets, int* __restrict__ blocksums){
  __shared__ int sdata[1024];
  int i = blockIdx.x*1024 + threadIdx.x;
  int v = (i<N) ? counts[i] : 0;
  sdata[threadIdx.x] = v;
  __syncthreads();
  for(int off=1; off<1024; off<<=1){
    int t = (threadIdx.x >= off) ? sdata[threadIdx.x-off] : 0;
    __syncthreads();
    sdata[threadIdx.x] += t;
    __syncthreads();
  }
  if(i<N) offsets[i] = sdata[threadIdx.x] - v;
  if(threadIdx.x==1023) blocksums[blockIdx.x] = sdata[1023];
}

__global__ void scan2_kernel(int* __restrict__ blocksums, int nb){
  __shared__ int sdata[64];
  int v = ((int)threadIdx.x < nb) ? blocksums[threadIdx.x] : 0;
  sdata[threadIdx.x] = v;
  __syncthreads();
  for(int off=1; off<64; off<<=1){
    int t = (threadIdx.x >= off) ? sdata[threadIdx.x-off] : 0;
    __syncthreads();
    sdata[threadIdx.x] += t;
    __syncthreads();
  }
  if((int)threadIdx.x < nb) blocksums[threadIdx.x] = sdata[threadIdx.x] - v;
}

__global__ void scan3_kernel(int* __restrict__ offsets, const int* __restrict__ blocksums,
                             int N, int E, int* __restrict__ cursor){
  int i = blockIdx.x*1024 + threadIdx.x;
  if(i < N){
    int o = offsets[i] + blocksums[blockIdx.x];
    offsets[i] = o;
    cursor[i] = o;
  }
  if(i == 0) offsets[N] = E;
}

__global__ void scatter_kernel(const int* __restrict__ src, const int* __restrict__ dst, int E,
                               int* __restrict__ cursor, int* __restrict__ ssrc,
                               int* __restrict__ sdst){
  int i = blockIdx.x*blockDim.x + threadIdx.x;
  if(i < E){
    int d = dst[i];
    int p = atomicAdd(&cursor[d], 1);
    ssrc[p] = src[i];
    sdst[p] = d;
  }
}

// ---------------- W split to packed fragment order: W[K=256, N] -> packed[16 ntiles] ----------------
__global__ __launch_bounds__(256) void wsplit_pack(const float* __restrict__ W, int N,
                              ushortT* __restrict__ Wh, ushortT* __restrict__ Wl){
  int idx = blockIdx.x*256 + threadIdx.x;     // < 16*8*64 = 8192
  int lane = idx & 63;
  int t  = (idx >> 6) & 7;
  int nt = idx >> 9;
  int l15 = lane & 15, quad = lane >> 4;
  int n = nt*16 + l15;
  ushortT h[8], l[8];
  #pragma unroll
  for(int j=0;j<8;j++){
    int k = t*32 + quad*8 + j;
    float v = (n < N) ? W[(size_t)k*N + n] : 0.f;
    h[j] = f2bf(v);
    l[j] = f2bf(v - bf2f(h[j]));
  }
  *(short8*)&Wh[(size_t)idx*8] = *(short8*)h;
  *(short8*)&Wl[(size_t)idx*8] = *(short8*)l;
}

// ---------------- x split fp32 [M][256] -> A-plane layout [t][Mpad][32] ----------------
__global__ __launch_bounds__(256) void xsplit_pack(const float* __restrict__ x, int M, int Mpad,
                              ushortT* __restrict__ Xh, ushortT* __restrict__ Xl){
  int idx = blockIdx.x*256 + threadIdx.x;     // over 8*Mpad, idx = t*Mpad + m
  if(idx >= 8*Mpad) return;
  int t = idx / Mpad, m = idx - t*Mpad;
  size_t base = (size_t)idx * 32;
  if(m < M){
    const float* xr = &x[(size_t)m*256 + t*32];
    #pragma unroll
    for(int c=0;c<4;c++){
      float4 v0 = *(const float4*)&xr[c*8];
      float4 v1 = *(const float4*)&xr[c*8+4];
      float vv[8] = {v0.x,v0.y,v0.z,v0.w,v1.x,v1.y,v1.z,v1.w};
      ushortT h[8], l[8];
      #pragma unroll
      for(int j=0;j<8;j++){
        h[j] = f2bf(vv[j]);
        l[j] = f2bf(vv[j] - bf2f(h[j]));
      }
      *(short8*)&Xh[base + c*8] = *(short8*)h;
      *(short8*)&Xl[base + c*8] = *(short8*)l;
    }
  } else {
    short8 z = {0,0,0,0,0,0,0,0};
    #pragma unroll
    for(int c=0;c<4;c++){ *(short8*)&Xh[base + c*8] = z; *(short8*)&Xl[base + c*8] = z; }
  }
}

// ---------------- bf16x3 MFMA GEMM, A read ONCE: block = 32 rows x full 256 cols ----------------
__global__ __launch_bounds__(256) void gemm_packed(
    const ushortT* __restrict__ Ah, const ushortT* __restrict__ Al,
    const ushortT* __restrict__ Bh, const ushortT* __restrict__ Bl,
    ushortT* __restrict__ Cm, int M, int Mpad, int N,
    const float* __restrict__ al, const float* __restrict__ ar,
    float* __restrict__ el, float* __restrict__ er){
  const int lane = threadIdx.x & 63;
  const int wv   = threadIdx.x >> 6;
  const int l15  = lane & 15, quad = lane >> 4;
  const int m0   = blockIdx.x*32;
  const int n0   = wv*64;
  const int nt0  = n0 >> 4;     // 4 ntiles per wave

  f32x4 acc[2][4];
  #pragma unroll
  for(int i=0;i<2;i++)
    #pragma unroll
    for(int j=0;j<4;j++){ acc[i][j][0]=0.f; acc[i][j][1]=0.f; acc[i][j][2]=0.f; acc[i][j][3]=0.f; }

  #pragma unroll
  for(int t=0; t<8; t++){
    short8 a_h[2], a_l[2], b_h[4], b_l[4];
    #pragma unroll
    for(int i=0;i<2;i++){
      size_t ad = ((size_t)t*Mpad + (m0 + i*16 + l15))*32 + quad*8;
      a_h[i] = *(const short8*)&Ah[ad];
      a_l[i] = *(const short8*)&Al[ad];
    }
    #pragma unroll
    for(int j=0;j<4;j++){
      size_t bd = (((size_t)(nt0+j)*8 + t)*64 + lane)*8;
      b_h[j] = *(const short8*)&Bh[bd];
      b_l[j] = *(const short8*)&Bl[bd];
    }
    #pragma unroll
    for(int i=0;i<2;i++)
      #pragma unroll
      for(int j=0;j<4;j++){
        acc[i][j] = __builtin_amdgcn_mfma_f32_16x16x32_bf16(a_h[i], b_h[j], acc[i][j], 0,0,0);
        acc[i][j] = __builtin_amdgcn_mfma_f32_16x16x32_bf16(a_h[i], b_l[j], acc[i][j], 0,0,0);
        acc[i][j] = __builtin_amdgcn_mfma_f32_16x16x32_bf16(a_l[i], b_h[j], acc[i][j], 0,0,0);
      }
  }

  // fused el/er (layers 0/1): this wave's col-tile is exactly head wv
  if(al){
    const int h = wv;
    float alv[4], arv[4];
    #pragma unroll
    for(int j=0;j<4;j++){
      alv[j] = al[h*64 + j*16 + l15];
      arv[j] = ar[h*64 + j*16 + l15];
    }
    #pragma unroll
    for(int i=0;i<2;i++){
      #pragma unroll
      for(int r=0;r<4;r++){
        float pl = acc[i][0][r]*alv[0] + acc[i][1][r]*alv[1]
                 + acc[i][2][r]*alv[2] + acc[i][3][r]*alv[3];
        float pr = acc[i][0][r]*arv[0] + acc[i][1][r]*arv[1]
                 + acc[i][2][r]*arv[2] + acc[i][3][r]*arv[3];
        #pragma unroll
        for(int off=1; off<16; off<<=1){ pl += __shfl_xor(pl,off); pr += __shfl_xor(pr,off); }
        int gm = m0 + i*16 + quad*4 + r;
        if(l15==0 && gm < M){ el[gm*4+h] = pl; er[gm*4+h] = pr; }
      }
    }
  }

  // C store, row-major bf16.  C/D layout: col=lane&15, row=quad*4+r
  #pragma unroll
  for(int i=0;i<2;i++){
    #pragma unroll
    for(int r=0;r<4;r++){
      int gm = m0 + i*16 + quad*4 + r;
      if(gm >= M) continue;
      #pragma unroll
      for(int j=0;j<4;j++){
        int gn = n0 + j*16 + l15;
        if(gn < N) Cm[(size_t)gm*N + gn] = f2bf(acc[i][j][r]);
      }
    }
  }
}

// ---------------- el/er projection from bf16 feat (layer 2 only) ----------------
__global__ void attn_proj_bf(const __hip_bfloat16* __restrict__ feat, const float* __restrict__ a_l,
                             const float* __restrict__ a_r, float* __restrict__ el,
                             float* __restrict__ er, int D){
  int n = blockIdx.x;
  int h = threadIdx.x >> 6;
  int lane = threadIdx.x & 63;
  float vl = 0.f, vr = 0.f;
  for(int d=lane; d<D; d+=64){
    float f = (float)feat[(size_t)n*4*D + h*D + d];
    vl = fmaf(f, a_l[h*D+d], vl);
    vr = fmaf(f, a_r[h*D+d], vr);
  }
  #pragma unroll
  for(int off=32; off; off>>=1){ vl += __shfl_down(vl,off); vr += __shfl_down(vr,off); }
  if(lane==0){ el[n*4+h] = vl; er[n*4+h] = vr; }
}

// ---------------- per-edge softmax numerators, HEAD-MAJOR planes ewp[h][e] ----------------
// (head-major so agg can fetch 4 edges' weights with ONE float4 load)
__global__ __launch_bounds__(256) void edge_w_kernel(const int* __restrict__ ssrc,
                              const int* __restrict__ sdst, int E,
                              const float4* __restrict__ el4, const float4* __restrict__ er4,
                              float* __restrict__ ewp){
  int e = blockIdx.x*blockDim.x + threadIdx.x;
  if(e >= E) return;
  int s = ssrc[e], d = sdst[e];
  float4 l = el4[s], r = er4[d];
  ewp[e]              = __expf(leaky(l.x + r.x));
  ewp[(size_t)E + e]  = __expf(leaky(l.y + r.y));
  ewp[(size_t)2*E + e]= __expf(leaky(l.z + r.z));
  ewp[(size_t)3*E + e]= __expf(leaky(l.w + r.w));
}

// ---------------- softmax + aggregate, layers 0/1 (H*D=256 bf16), ELU ----------------
// One WAVE per dst node; 2 edge-slots x 32 dim-lanes (16B uint4 per lane = 8 dims).
// Per 8-edge iteration: 1 int4 (src idx) + 1 float4 (weights, head-major) + 4 uint4
// gathers per slot -> ~6.5 wave-instr/edge vs ~11 in the 8B/lane version.
// Epilogue: single off=32 shuffle-reduce, slot-0 lanes store hi/lo A-planes (16B each).
__global__ __launch_bounds__(256) void agg_kernel(const uint4* __restrict__ feat4,
                           const float* __restrict__ ewp,
                           const int* __restrict__ offsets, const int* __restrict__ ssrc,
                           const float* __restrict__ bias,
                           ushortT* __restrict__ Hh, ushortT* __restrict__ Hl,
                           int N, int Mpad, int E){
  int wvi  = threadIdx.x >> 6;
  int lane = threadIdx.x & 63;
  int n = blockIdx.x*4 + wvi;
  if(n >= N) return;
  const int slot = lane >> 5;          // edge slot 0/1
  const int wl   = lane & 31;          // dim-lane: owns dims wl*8..wl*8+7
  const int head = wl >> 3;            // 8 lanes per head (64 dims / 8 per lane)
  const float* __restrict__ wh = ewp + (size_t)head * E;
  int e0 = offsets[n], e1 = offsets[n+1];
  float a0=0.f,a1=0.f,a2=0.f,a3=0.f,a4=0.f,a5=0.f,a6=0.f,a7=0.f;
  float den = 0.f;
  int e = e0;
  for(; e+7 < e1; e += 8){
    int4u sv = *(const int4u*)&ssrc[e + slot*4];
    f4u   wv = *(const f4u*)  &wh[e + slot*4];
    #pragma unroll
    for(int i=0;i<4;i++){
      uint4 q = feat4[(size_t)sv[i]*32 + wl];
      float w = wv[i];
      a0 = fmaf(w, bf_lo(q.x), a0); a1 = fmaf(w, bf_hi(q.x), a1);
      a2 = fmaf(w, bf_lo(q.y), a2); a3 = fmaf(w, bf_hi(q.y), a3);
      a4 = fmaf(w, bf_lo(q.z), a4); a5 = fmaf(w, bf_hi(q.z), a5);
      a6 = fmaf(w, bf_lo(q.w), a6); a7 = fmaf(w, bf_hi(q.w), a7);
      den += w;
    }
  }
  for(; e < e1; e += 2){              // tail: <=4 iterations (remainder <8)
    int ee = e + slot;
    int ec = (ee < e1) ? ee : (e1 - 1);     // clamp: safe row, weight zeroed
    float w = (ee < e1) ? wh[ec] : 0.f;
    int s = ssrc[ec];
    uint4 q = feat4[(size_t)s*32 + wl];
    a0 = fmaf(w, bf_lo(q.x), a0); a1 = fmaf(w, bf_hi(q.x), a1);
    a2 = fmaf(w, bf_lo(q.y), a2); a3 = fmaf(w, bf_hi(q.y), a3);
    a4 = fmaf(w, bf_lo(q.z), a4); a5 = fmaf(w, bf_hi(q.z), a5);
    a6 = fmaf(w, bf_lo(q.w), a6); a7 = fmaf(w, bf_hi(q.w), a7);
    den += w;
  }
  // combine the two edge slots
  a0 += __shfl_xor(a0,32); a1 += __shfl_xor(a1,32);
  a2 += __shfl_xor(a2,32); a3 += __shfl_xor(a3,32);
  a4 += __shfl_xor(a4,32); a5 += __shfl_xor(a5,32);
  a6 += __shfl_xor(a6,32); a7 += __shfl_xor(a7,32);
  den += __shfl_xor(den,32);
  if(slot == 0){
    float inv = 1.f / fmaxf(den, 1e-9f);
    int k0 = wl*8;
    float4 b4a = *(const float4*)&bias[k0];
    float4 b4b = *(const float4*)&bias[k0+4];
    float o[8];
    o[0] = elu(a0*inv + b4a.x); o[1] = elu(a1*inv + b4a.y);
    o[2] = elu(a2*inv + b4a.z); o[3] = elu(a3*inv + b4a.w);
    o[4] = elu(a4*inv + b4b.x); o[5] = elu(a5*inv + b4b.y);
    o[6] = elu(a6*inv + b4b.z); o[7] = elu(a7*inv + b4b.w);
    ushortT hh[8], ll[8];
    #pragma unroll
    for(int j=0;j<8;j++){
      hh[j] = f2bf(o[j]);
      ll[j] = f2bf(o[j] - bf2f(hh[j]));
    }
    // A-plane store: dims k0..k0+7 -> t=k0/32, chunk offset k0%32 (16B-aligned)
    int t  = wl >> 2;
    int co = (wl & 3) * 8;
    size_t ad = ((size_t)t*Mpad + n)*32 + co;
    *(short8*)&Hh[ad] = *(short8*)hh;
    *(short8*)&Hl[ad] = *(short8*)ll;
  }
}

// ---------------- layer 2: aggregate (H*C=160 bf16) + head-mean logits ----------------
__global__ __launch_bounds__(256) void agg2_kernel(const uint2* __restrict__ feat2,
                            const float* __restrict__ ewp,
                            const int* __restrict__ offsets, const int* __restrict__ ssrc,
                            const float* __restrict__ bias, float* __restrict__ logits,
                            int N, int E){
  __shared__ float s_out[4][160];
  int wv = threadIdx.x >> 6;
  int lane = threadIdx.x & 63;
  int n = blockIdx.x*4 + wv;
  bool valid = (n < N);
  if(valid && lane < 40){
    int h = lane / 10;
    const float* __restrict__ wh = ewp + (size_t)h * E;
    int e0 = offsets[n], e1 = offsets[n+1];
    float4 acc0 = make_float4(0.f,0.f,0.f,0.f), acc1 = acc0, acc2 = acc0, acc3 = acc0;
    float den0 = 0.f, den1 = 0.f, den2 = 0.f, den3 = 0.f;
    int e = e0;
    for(; e+3 < e1; e += 4){
      int s0 = ssrc[e], s1 = ssrc[e+1], s2 = ssrc[e+2], s3 = ssrc[e+3];
      float w0 = wh[e];
      float w1 = wh[e+1];
      float w2 = wh[e+2];
      float w3 = wh[e+3];
      uint2 q0 = feat2[(size_t)s0*40 + lane];
      uint2 q1 = feat2[(size_t)s1*40 + lane];
      uint2 q2 = feat2[(size_t)s2*40 + lane];
      uint2 q3 = feat2[(size_t)s3*40 + lane];
      acc0.x = fmaf(w0,bf_lo(q0.x),acc0.x); acc0.y = fmaf(w0,bf_hi(q0.x),acc0.y);
      acc0.z = fmaf(w0,bf_lo(q0.y),acc0.z); acc0.w = fmaf(w0,bf_hi(q0.y),acc0.w); den0 += w0;
      acc1.x = fmaf(w1,bf_lo(q1.x),acc1.x); acc1.y = fmaf(w1,bf_hi(q1.x),acc1.y);
      acc1.z = fmaf(w1,bf_lo(q1.y),acc1.z); acc1.w = fmaf(w1,bf_hi(q1.y),acc1.w); den1 += w1;
      acc2.x = fmaf(w2,bf_lo(q2.x),acc2.x); acc2.y = fmaf(w2,bf_hi(q2.x),acc2.y);
      acc2.z = fmaf(w2,bf_lo(q2.y),acc2.z); acc2.w = fmaf(w2,bf_hi(q2.y),acc2.w); den2 += w2;
      acc3.x = fmaf(w3,bf_lo(q3.x),acc3.x); acc3.y = fmaf(w3,bf_hi(q3.x),acc3.y);
      acc3.z = fmaf(w3,bf_lo(q3.y),acc3.z); acc3.w = fmaf(w3,bf_hi(q3.y),acc3.w); den3 += w3;
    }
    for(; e < e1; e++){
      int s = ssrc[e];
      float w = wh[e];
      uint2 q = feat2[(size_t)s*40 + lane];
      acc0.x = fmaf(w,bf_lo(q.x),acc0.x); acc0.y = fmaf(w,bf_hi(q.x),acc0.y);
      acc0.z = fmaf(w,bf_lo(q.y),acc0.z); acc0.w = fmaf(w,bf_hi(q.y),acc0.w); den0 += w;
    }
    float denom = (den0+den1) + (den2+den3);
    float4 acc;
    acc.x = (acc0.x+acc1.x) + (acc2.x+acc3.x);
    acc.y = (acc0.y+acc1.y) + (acc2.y+acc3.y);
    acc.z = (acc0.z+acc1.z) + (acc2.z+acc3.z);
    acc.w = (acc0.w+acc1.w) + (acc2.w+acc3.w);
    float inv = 1.f / fmaxf(denom, 1e-9f);
    float4 b4 = *(const float4*)&bias[lane*4];
    s_out[wv][lane*4+0] = acc.x*inv + b4.x;
    s_out[wv][lane*4+1] = acc.y*inv + b4.y;
    s_out[wv][lane*4+2] = acc.z*inv + b4.z;
    s_out[wv][lane*4+3] = acc.w*inv + b4.w;
  }
  __syncthreads();
  if(valid && lane < 40){
    logits[(size_t)n*40 + lane] =
        0.25f * (s_out[wv][lane] + s_out[wv][40+lane] + s_out[wv][80+lane] + s_out[wv][120+lane]);
  }
}

extern "C" void kernel_launch(void* const* d_in, const int* in_sizes, int n_in,
                              void* d_out, int out_size, void* d_ws, size_t ws_size,
                              hipStream_t stream){
  const float* x   = (const float*)d_in[0];
  const int*   eix = (const int*)  d_in[1];
  const float* W0  = (const float*)d_in[2];
  const float* al0 = (const float*)d_in[3];
  const float* ar0 = (const float*)d_in[4];
  const float* b0  = (const float*)d_in[5];
  const float* W1  = (const float*)d_in[6];
  const float* al1 = (const float*)d_in[7];
  const float* ar1 = (const float*)d_in[8];
  const float* b1  = (const float*)d_in[9];
  const float* W2  = (const float*)d_in[10];
  const float* al2 = (const float*)d_in[11];
  const float* ar2 = (const float*)d_in[12];
  const float* b2  = (const float*)d_in[13];
  float* logits = (float*)d_out;

  const int N = in_sizes[0] / 256;   // 50000
  const int E = in_sizes[1] / 2;     // 800000
  const int* src = eix;
  const int* dst = eix + E;
  const int nb = (N + 1023) / 1024;

  char* ws = (char*)d_ws;
  auto alloc = [&](size_t bytes)->char*{
    char* p = ws; ws += (bytes + 255) & ~(size_t)255; return p;
  };
  const int nblocksM = (N + 127)/128;
  const int Mpad = nblocksM * 128;
  const size_t apackElems = (size_t)Mpad * 256;
  int*   counts    = (int*)  alloc((size_t)N*4);
  int*   offsets   = (int*)  alloc((size_t)(N+1)*4);
  int*   cursor    = (int*)  alloc((size_t)N*4);
  int*   blocksums = (int*)  alloc((size_t)nb*4);
  int*   ssrc      = (int*)  alloc((size_t)E*4);
  int*   sdst      = (int*)  alloc((size_t)E*4);
  float* ew        = (float*)alloc((size_t)E*4*4);                  // 4 head-major planes [4][E]
  __hip_bfloat16* bufF = (__hip_bfloat16*)alloc((size_t)N*256*2);   // gemm output (bf16, row-major)
  ushortT* Hh      = (ushortT*)alloc(apackElems*2);                  // A hi plane [t][Mpad][32]
  ushortT* Hl      = (ushortT*)alloc(apackElems*2);                  // A lo plane
  float* el_buf    = (float*)alloc((size_t)N*4*4);
  float* er_buf    = (float*)alloc((size_t)N*4*4);
  ushortT* Wph0 = (ushortT*)alloc(16*8*64*8*2);
  ushortT* Wpl0 = (ushortT*)alloc(16*8*64*8*2);
  ushortT* Wph1 = (ushortT*)alloc(16*8*64*8*2);
  ushortT* Wpl1 = (ushortT*)alloc(16*8*64*8*2);
  ushortT* Wph2 = (ushortT*)alloc(16*8*64*8*2);
  ushortT* Wpl2 = (ushortT*)alloc(16*8*64*8*2);

  // sort edges by dst (graph fixed across layers — one sort per call)
  hipMemsetAsync(counts, 0, (size_t)N*4, stream);
  hist_kernel   <<<(E+255)/256, 256, 0, stream>>>(dst, E, counts);
  scan1_kernel  <<<nb, 1024, 0, stream>>>(counts, N, offsets, blocksums);
  scan2_kernel  <<<1, 64, 0, stream>>>(blocksums, nb);
  scan3_kernel  <<<nb, 1024, 0, stream>>>(offsets, blocksums, N, E, cursor);
  scatter_kernel<<<(E+255)/256, 256, 0, stream>>>(src, dst, E, cursor, ssrc, sdst);

  // weight + x packing (fragment order, hi/lo split)
  wsplit_pack<<<32, 256, 0, stream>>>(W0, 256, Wph0, Wpl0);
  wsplit_pack<<<32, 256, 0, stream>>>(W1, 256, Wph1, Wpl1);
  wsplit_pack<<<32, 256, 0, stream>>>(W2, 160, Wph2, Wpl2);
  int xtotal = 8 * Mpad;
  xsplit_pack<<<(xtotal+255)/256, 256, 0, stream>>>(x, N, Mpad, Hh, Hl);

  int ggBlocks = Mpad / 32;        // block = 32 rows x full-N; A read exactly once
  int aggGrid  = (N+3)/4;
  int ewGrid  = (E+255)/256;
  // layer 0 (el/er fused in gemm epilogue)
  gemm_packed<<<ggBlocks, 256, 0, stream>>>(Hh, Hl, Wph0, Wpl0, (ushortT*)bufF, N, Mpad, 256, al0, ar0, el_buf, er_buf);
  edge_w_kernel<<<ewGrid, 256, 0, stream>>>(ssrc, sdst, E, (const float4*)el_buf, (const float4*)er_buf, ew);
  agg_kernel<<<aggGrid, 256, 0, stream>>>((const uint4*)bufF, ew, offsets, ssrc, b0, Hh, Hl, N, Mpad, E);
  // layer 1
  gemm_packed<<<ggBlocks, 256, 0, stream>>>(Hh, Hl, Wph1, Wpl1, (ushortT*)bufF, N, Mpad, 256, al1, ar1, el_buf, er_buf);
  edge_w_kernel<<<ewGrid, 256, 0, stream>>>(ssrc, sdst, E, (const float4*)el_buf, (const float4*)er_buf, ew);
  agg_kernel<<<aggGrid, 256, 0, stream>>>((const uint4*)bufF, ew, offsets, ssrc, b1, Hh, Hl, N, Mpad, E);
  // layer 2 (N=160: waves 2/3 partially idle on zero-padded B cols; stores guarded)
  gemm_packed<<<ggBlocks, 256, 0, stream>>>(Hh, Hl, Wph2, Wpl2, (ushortT*)bufF, N, Mpad, 160, nullptr, nullptr, nullptr, nullptr);
  attn_proj_bf<<<N, 256, 0, stream>>>(bufF, al2, ar2, el_buf, er_buf, 40);
  edge_w_kernel<<<ewGrid, 256, 0, stream>>>(ssrc, sdst, E, (const float4*)el_buf, (const float4*)er_buf, ew);
  agg2_kernel<<<aggGrid, 256, 0, stream>>>((const uint2*)bufF, ew, offsets, ssrc, b2, logits, N, E);
}

// Round 3
// 545.856 us; speedup vs baseline: 1.6439x; 1.0383x over previous
//
#include <hip/hip_runtime.h>
#include <hip/hip_bf16.h>
#include <math.h>

#define NEG_SLOPE 0.2f

typedef unsigned short ushortT;
typedef __attribute__((ext_vector_type(8))) short short8;   // 8 bf16 = 4 VGPRs (MFMA A/B frag)
typedef __attribute__((ext_vector_type(4))) float f32x4;    // MFMA C/D frag
typedef __attribute__((ext_vector_type(4), aligned(4))) int   int4u;   // 4B-aligned int4 load

static __device__ __forceinline__ float leaky(float x){ return x > 0.f ? x : NEG_SLOPE * x; }
static __device__ __forceinline__ float elu(float x){ return x > 0.f ? x : (__expf(x) - 1.f); }

// bf16 helpers: RNE pack, exact unpack
static __device__ __forceinline__ ushortT f2bf(float f){
  unsigned u = __float_as_uint(f);
  u += 0x7fff + ((u >> 16) & 1);
  return (ushortT)(u >> 16);
}
static __device__ __forceinline__ float bf2f(ushortT h){ return __uint_as_float((unsigned)h << 16); }
static __device__ __forceinline__ float bf_lo(unsigned u){ return __uint_as_float(u << 16); }
static __device__ __forceinline__ float bf_hi(unsigned u){ return __uint_as_float(u & 0xffff0000u); }

// A-plane layout: elem (row,k) -> [ (k/32)*Mpad + row ]*32 + k%32
//   (GEMM frag-loadable AND 64B-line-contiguous for agg stores — zero RMW)
// B-plane layout: [(ntile*8 + t)*64 + lane]*8 (contiguous 1KB per wave frag)

// ---------------- edge sort by dst (counting sort) ----------------
__global__ void hist_kernel(const int* __restrict__ dst, int E, int* __restrict__ counts){
  int i = blockIdx.x*blockDim.x + threadIdx.x;
  if(i < E) atomicAdd(&counts[dst[i]], 1);
}

__global__ void scan1_kernel(const int* __restrict__ counts, int N,
                             int* __restrict__ offsets, int* __restrict__ blocksums){
  __shared__ int sdata[1024];
  int i = blockIdx.x*1024 + threadIdx.x;
  int v = (i<N) ? counts[i] : 0;
  sdata[threadIdx.x] = v;
  __syncthreads();
  for(int off=1; off<1024; off<<=1){
    int t = (threadIdx.x >= off) ? sdata[threadIdx.x-off] : 0;
    __syncthreads();
    sdata[threadIdx.x] += t;
    __syncthreads();
  }
  if(i<N) offsets[i] = sdata[threadIdx.x] - v;
  if(threadIdx.x==1023) blocksums[blockIdx.x] = sdata[1023];
}

__global__ void scan2_kernel(int* __restrict__ blocksums, int nb){
  __shared__ int sdata[64];
  int v = ((int)threadIdx.x < nb) ? blocksums[threadIdx.x] : 0;
  sdata[threadIdx.x] = v;
  __syncthreads();
  for(int off=1; off<64; off<<=1){
    int t = (threadIdx.x >= off) ? sdata[threadIdx.x-off] : 0;
    __syncthreads();
    sdata[threadIdx.x] += t;
    __syncthreads();
  }
  if((int)threadIdx.x < nb) blocksums[threadIdx.x] = sdata[threadIdx.x] - v;
}

__global__ void scan3_kernel(int* __restrict__ offsets, const int* __restrict__ blocksums,
                             int N, int E, int* __restrict__ cursor){
  int i = blockIdx.x*1024 + threadIdx.x;
  if(i < N){
    int o = offsets[i] + blocksums[blockIdx.x];
    offsets[i] = o;
    cursor[i] = o;
  }
  if(i == 0) offsets[N] = E;
}

__global__ void scatter_kernel(const int* __restrict__ src, const int* __restrict__ dst, int E,
                               int* __restrict__ cursor, int* __restrict__ ssrc){
  int i = blockIdx.x*blockDim.x + threadIdx.x;
  if(i < E){
    int d = dst[i];
    int p = atomicAdd(&cursor[d], 1);
    ssrc[p] = src[i];
  }
}

// ---------------- W split to packed fragment order: W[K=256, N] -> packed[16 ntiles] ----------------
__global__ __launch_bounds__(256) void wsplit_pack(const float* __restrict__ W, int N,
                              ushortT* __restrict__ Wh, ushortT* __restrict__ Wl){
  int idx = blockIdx.x*256 + threadIdx.x;     // < 16*8*64 = 8192
  int lane = idx & 63;
  int t  = (idx >> 6) & 7;
  int nt = idx >> 9;
  int l15 = lane & 15, quad = lane >> 4;
  int n = nt*16 + l15;
  ushortT h[8], l[8];
  #pragma unroll
  for(int j=0;j<8;j++){
    int k = t*32 + quad*8 + j;
    float v = (n < N) ? W[(size_t)k*N + n] : 0.f;
    h[j] = f2bf(v);
    l[j] = f2bf(v - bf2f(h[j]));
  }
  *(short8*)&Wh[(size_t)idx*8] = *(short8*)h;
  *(short8*)&Wl[(size_t)idx*8] = *(short8*)l;
}

// ---------------- x split fp32 [M][256] -> A-plane layout [t][Mpad][32] ----------------
__global__ __launch_bounds__(256) void xsplit_pack(const float* __restrict__ x, int M, int Mpad,
                              ushortT* __restrict__ Xh, ushortT* __restrict__ Xl){
  int idx = blockIdx.x*256 + threadIdx.x;     // over 8*Mpad, idx = t*Mpad + m
  if(idx >= 8*Mpad) return;
  int t = idx / Mpad, m = idx - t*Mpad;
  size_t base = (size_t)idx * 32;
  if(m < M){
    const float* xr = &x[(size_t)m*256 + t*32];
    #pragma unroll
    for(int c=0;c<4;c++){
      float4 v0 = *(const float4*)&xr[c*8];
      float4 v1 = *(const float4*)&xr[c*8+4];
      float vv[8] = {v0.x,v0.y,v0.z,v0.w,v1.x,v1.y,v1.z,v1.w};
      ushortT h[8], l[8];
      #pragma unroll
      for(int j=0;j<8;j++){
        h[j] = f2bf(vv[j]);
        l[j] = f2bf(vv[j] - bf2f(h[j]));
      }
      *(short8*)&Xh[base + c*8] = *(short8*)h;
      *(short8*)&Xl[base + c*8] = *(short8*)l;
    }
  } else {
    short8 z = {0,0,0,0,0,0,0,0};
    #pragma unroll
    for(int c=0;c<4;c++){ *(short8*)&Xh[base + c*8] = z; *(short8*)&Xl[base + c*8] = z; }
  }
}

// ---------------- bf16x3 MFMA GEMM, A read ONCE: block = 32 rows x full 256 cols ----------------
__global__ __launch_bounds__(256) void gemm_packed(
    const ushortT* __restrict__ Ah, const ushortT* __restrict__ Al,
    const ushortT* __restrict__ Bh, const ushortT* __restrict__ Bl,
    ushortT* __restrict__ Cm, int M, int Mpad, int N,
    const float* __restrict__ al, const float* __restrict__ ar,
    float* __restrict__ el, float* __restrict__ er){
  const int lane = threadIdx.x & 63;
  const int wv   = threadIdx.x >> 6;
  const int l15  = lane & 15, quad = lane >> 4;
  const int m0   = blockIdx.x*32;
  const int n0   = wv*64;
  const int nt0  = n0 >> 4;     // 4 ntiles per wave

  f32x4 acc[2][4];
  #pragma unroll
  for(int i=0;i<2;i++)
    #pragma unroll
    for(int j=0;j<4;j++){ acc[i][j][0]=0.f; acc[i][j][1]=0.f; acc[i][j][2]=0.f; acc[i][j][3]=0.f; }

  #pragma unroll
  for(int t=0; t<8; t++){
    short8 a_h[2], a_l[2], b_h[4], b_l[4];
    #pragma unroll
    for(int i=0;i<2;i++){
      size_t ad = ((size_t)t*Mpad + (m0 + i*16 + l15))*32 + quad*8;
      a_h[i] = *(const short8*)&Ah[ad];
      a_l[i] = *(const short8*)&Al[ad];
    }
    #pragma unroll
    for(int j=0;j<4;j++){
      size_t bd = (((size_t)(nt0+j)*8 + t)*64 + lane)*8;
      b_h[j] = *(const short8*)&Bh[bd];
      b_l[j] = *(const short8*)&Bl[bd];
    }
    #pragma unroll
    for(int i=0;i<2;i++)
      #pragma unroll
      for(int j=0;j<4;j++){
        acc[i][j] = __builtin_amdgcn_mfma_f32_16x16x32_bf16(a_h[i], b_h[j], acc[i][j], 0,0,0);
        acc[i][j] = __builtin_amdgcn_mfma_f32_16x16x32_bf16(a_h[i], b_l[j], acc[i][j], 0,0,0);
        acc[i][j] = __builtin_amdgcn_mfma_f32_16x16x32_bf16(a_l[i], b_h[j], acc[i][j], 0,0,0);
      }
  }

  // fused el/er (layers 0/1): this wave's col-tile is exactly head wv
  if(al){
    const int h = wv;
    float alv[4], arv[4];
    #pragma unroll
    for(int j=0;j<4;j++){
      alv[j] = al[h*64 + j*16 + l15];
      arv[j] = ar[h*64 + j*16 + l15];
    }
    #pragma unroll
    for(int i=0;i<2;i++){
      #pragma unroll
      for(int r=0;r<4;r++){
        float pl = acc[i][0][r]*alv[0] + acc[i][1][r]*alv[1]
                 + acc[i][2][r]*alv[2] + acc[i][3][r]*alv[3];
        float pr = acc[i][0][r]*arv[0] + acc[i][1][r]*arv[1]
                 + acc[i][2][r]*arv[2] + acc[i][3][r]*arv[3];
        #pragma unroll
        for(int off=1; off<16; off<<=1){ pl += __shfl_xor(pl,off); pr += __shfl_xor(pr,off); }
        int gm = m0 + i*16 + quad*4 + r;
        if(l15==0 && gm < M){ el[gm*4+h] = pl; er[gm*4+h] = pr; }
      }
    }
  }

  // C store, row-major bf16.  C/D layout: col=lane&15, row=quad*4+r
  #pragma unroll
  for(int i=0;i<2;i++){
    #pragma unroll
    for(int r=0;r<4;r++){
      int gm = m0 + i*16 + quad*4 + r;
      if(gm >= M) continue;
      #pragma unroll
      for(int j=0;j<4;j++){
        int gn = n0 + j*16 + l15;
        if(gn < N) Cm[(size_t)gm*N + gn] = f2bf(acc[i][j][r]);
      }
    }
  }
}

// ---------------- el/er projection from bf16 feat (layer 2 only) ----------------
__global__ void attn_proj_bf(const __hip_bfloat16* __restrict__ feat, const float* __restrict__ a_l,
                             const float* __restrict__ a_r, float* __restrict__ el,
                             float* __restrict__ er, int D){
  int n = blockIdx.x;
  int h = threadIdx.x >> 6;
  int lane = threadIdx.x & 63;
  float vl = 0.f, vr = 0.f;
  for(int d=lane; d<D; d+=64){
    float f = (float)feat[(size_t)n*4*D + h*D + d];
    vl = fmaf(f, a_l[h*D+d], vl);
    vr = fmaf(f, a_r[h*D+d], vr);
  }
  #pragma unroll
  for(int off=32; off; off>>=1){ vl += __shfl_down(vl,off); vr += __shfl_down(vr,off); }
  if(lane==0){ el[n*4+h] = vl; er[n*4+h] = vr; }
}

// ---------------- softmax + aggregate, layers 0/1 (H*D=256 bf16), ELU ----------------
// Edge-weight computation FUSED (edge_w kernel removed): w = exp(leaky(el[s]+er[n])).
// el table is N*16B = 800KB -> L2-resident per XCD; el[s*4+head] gather touches only
// ~2 distinct 16B regions per instruction (8 lanes/head share the address).
// One WAVE per dst node; 2 edge-slots x 32 dim-lanes (16B uint4 per lane = 8 dims).
__global__ __launch_bounds__(256) void agg_kernel(const uint4* __restrict__ feat4,
                           const float* __restrict__ el, const float* __restrict__ er,
                           const int* __restrict__ offsets, const int* __restrict__ ssrc,
                           const float* __restrict__ bias,
                           ushortT* __restrict__ Hh, ushortT* __restrict__ Hl,
                           int N, int Mpad){
  int wvi  = threadIdx.x >> 6;
  int lane = threadIdx.x & 63;
  int n = blockIdx.x*4 + wvi;
  if(n >= N) return;
  const int slot = lane >> 5;          // edge slot 0/1
  const int wl   = lane & 31;          // dim-lane: owns dims wl*8..wl*8+7
  const int head = wl >> 3;            // 8 lanes per head (64 dims / 8 per lane)
  const float ern = er[n*4 + head];    // wave-constant per lane
  int e0 = offsets[n], e1 = offsets[n+1];
  float a0=0.f,a1=0.f,a2=0.f,a3=0.f,a4=0.f,a5=0.f,a6=0.f,a7=0.f;
  float den = 0.f;
  int e = e0;
  for(; e+7 < e1; e += 8){
    int4u sv = *(const int4u*)&ssrc[e + slot*4];
    #pragma unroll
    for(int i=0;i<4;i++){
      int s = sv[i];
      float w = __expf(leaky(el[s*4 + head] + ern));
      uint4 q = feat4[(size_t)s*32 + wl];
      a0 = fmaf(w, bf_lo(q.x), a0); a1 = fmaf(w, bf_hi(q.x), a1);
      a2 = fmaf(w, bf_lo(q.y), a2); a3 = fmaf(w, bf_hi(q.y), a3);
      a4 = fmaf(w, bf_lo(q.z), a4); a5 = fmaf(w, bf_hi(q.z), a5);
      a6 = fmaf(w, bf_lo(q.w), a6); a7 = fmaf(w, bf_hi(q.w), a7);
      den += w;
    }
  }
  for(; e < e1; e += 2){              // tail: <=4 iterations (remainder <8)
    int ee = e + slot;
    int ec = (ee < e1) ? ee : (e1 - 1);     // clamp: safe row, weight zeroed
    int s = ssrc[ec];
    float w = (ee < e1) ? __expf(leaky(el[s*4 + head] + ern)) : 0.f;
    uint4 q = feat4[(size_t)s*32 + wl];
    a0 = fmaf(w, bf_lo(q.x), a0); a1 = fmaf(w, bf_hi(q.x), a1);
    a2 = fmaf(w, bf_lo(q.y), a2); a3 = fmaf(w, bf_hi(q.y), a3);
    a4 = fmaf(w, bf_lo(q.z), a4); a5 = fmaf(w, bf_hi(q.z), a5);
    a6 = fmaf(w, bf_lo(q.w), a6); a7 = fmaf(w, bf_hi(q.w), a7);
    den += w;
  }
  // combine the two edge slots
  a0 += __shfl_xor(a0,32); a1 += __shfl_xor(a1,32);
  a2 += __shfl_xor(a2,32); a3 += __shfl_xor(a3,32);
  a4 += __shfl_xor(a4,32); a5 += __shfl_xor(a5,32);
  a6 += __shfl_xor(a6,32); a7 += __shfl_xor(a7,32);
  den += __shfl_xor(den,32);
  if(slot == 0){
    float inv = 1.f / fmaxf(den, 1e-9f);
    int k0 = wl*8;
    float4 b4a = *(const float4*)&bias[k0];
    float4 b4b = *(const float4*)&bias[k0+4];
    float o[8];
    o[0] = elu(a0*inv + b4a.x); o[1] = elu(a1*inv + b4a.y);
    o[2] = elu(a2*inv + b4a.z); o[3] = elu(a3*inv + b4a.w);
    o[4] = elu(a4*inv + b4b.x); o[5] = elu(a5*inv + b4b.y);
    o[6] = elu(a6*inv + b4b.z); o[7] = elu(a7*inv + b4b.w);
    ushortT hh[8], ll[8];
    #pragma unroll
    for(int j=0;j<8;j++){
      hh[j] = f2bf(o[j]);
      ll[j] = f2bf(o[j] - bf2f(hh[j]));
    }
    // A-plane store: dims k0..k0+7 -> t=k0/32, chunk offset k0%32 (16B-aligned)
    int t  = wl >> 2;
    int co = (wl & 3) * 8;
    size_t ad = ((size_t)t*Mpad + n)*32 + co;
    *(short8*)&Hh[ad] = *(short8*)hh;
    *(short8*)&Hl[ad] = *(short8*)ll;
  }
}

// ---------------- layer 2: aggregate (H*C=160 bf16) + head-mean logits ----------------
// Edge-weight computation fused (same scheme as agg_kernel).
__global__ __launch_bounds__(256) void agg2_kernel(const uint2* __restrict__ feat2,
                            const float* __restrict__ el, const float* __restrict__ er,
                            const int* __restrict__ offsets, const int* __restrict__ ssrc,
                            const float* __restrict__ bias, float* __restrict__ logits,
                            int N){
  __shared__ float s_out[4][160];
  int wv = threadIdx.x >> 6;
  int lane = threadIdx.x & 63;
  int n = blockIdx.x*4 + wv;
  bool valid = (n < N);
  if(valid && lane < 40){
    int h = lane / 10;
    const float ern = er[n*4 + h];
    int e0 = offsets[n], e1 = offsets[n+1];
    float4 acc0 = make_float4(0.f,0.f,0.f,0.f), acc1 = acc0, acc2 = acc0, acc3 = acc0;
    float den0 = 0.f, den1 = 0.f, den2 = 0.f, den3 = 0.f;
    int e = e0;
    for(; e+3 < e1; e += 4){
      int s0 = ssrc[e], s1 = ssrc[e+1], s2 = ssrc[e+2], s3 = ssrc[e+3];
      float w0 = __expf(leaky(el[s0*4 + h] + ern));
      float w1 = __expf(leaky(el[s1*4 + h] + ern));
      float w2 = __expf(leaky(el[s2*4 + h] + ern));
      float w3 = __expf(leaky(el[s3*4 + h] + ern));
      uint2 q0 = feat2[(size_t)s0*40 + lane];
      uint2 q1 = feat2[(size_t)s1*40 + lane];
      uint2 q2 = feat2[(size_t)s2*40 + lane];
      uint2 q3 = feat2[(size_t)s3*40 + lane];
      acc0.x = fmaf(w0,bf_lo(q0.x),acc0.x); acc0.y = fmaf(w0,bf_hi(q0.x),acc0.y);
      acc0.z = fmaf(w0,bf_lo(q0.y),acc0.z); acc0.w = fmaf(w0,bf_hi(q0.y),acc0.w); den0 += w0;
      acc1.x = fmaf(w1,bf_lo(q1.x),acc1.x); acc1.y = fmaf(w1,bf_hi(q1.x),acc1.y);
      acc1.z = fmaf(w1,bf_lo(q1.y),acc1.z); acc1.w = fmaf(w1,bf_hi(q1.y),acc1.w); den1 += w1;
      acc2.x = fmaf(w2,bf_lo(q2.x),acc2.x); acc2.y = fmaf(w2,bf_hi(q2.x),acc2.y);
      acc2.z = fmaf(w2,bf_lo(q2.y),acc2.z); acc2.w = fmaf(w2,bf_hi(q2.y),acc2.w); den2 += w2;
      acc3.x = fmaf(w3,bf_lo(q3.x),acc3.x); acc3.y = fmaf(w3,bf_hi(q3.x),acc3.y);
      acc3.z = fmaf(w3,bf_lo(q3.y),acc3.z); acc3.w = fmaf(w3,bf_hi(q3.y),acc3.w); den3 += w3;
    }
    for(; e < e1; e++){
      int s = ssrc[e];
      float w = __expf(leaky(el[s*4 + h] + ern));
      uint2 q = feat2[(size_t)s*40 + lane];
      acc0.x = fmaf(w,bf_lo(q.x),acc0.x); acc0.y = fmaf(w,bf_hi(q.x),acc0.y);
      acc0.z = fmaf(w,bf_lo(q.y),acc0.z); acc0.w = fmaf(w,bf_hi(q.y),acc0.w); den0 += w;
    }
    float denom = (den0+den1) + (den2+den3);
    float4 acc;
    acc.x = (acc0.x+acc1.x) + (acc2.x+acc3.x);
    acc.y = (acc0.y+acc1.y) + (acc2.y+acc3.y);
    acc.z = (acc0.z+acc1.z) + (acc2.z+acc3.z);
    acc.w = (acc0.w+acc1.w) + (acc2.w+acc3.w);
    float inv = 1.f / fmaxf(denom, 1e-9f);
    float4 b4 = *(const float4*)&bias[lane*4];
    s_out[wv][lane*4+0] = acc.x*inv + b4.x;
    s_out[wv][lane*4+1] = acc.y*inv + b4.y;
    s_out[wv][lane*4+2] = acc.z*inv + b4.z;
    s_out[wv][lane*4+3] = acc.w*inv + b4.w;
  }
  __syncthreads();
  if(valid && lane < 40){
    logits[(size_t)n*40 + lane] =
        0.25f * (s_out[wv][lane] + s_out[wv][40+lane] + s_out[wv][80+lane] + s_out[wv][120+lane]);
  }
}

extern "C" void kernel_launch(void* const* d_in, const int* in_sizes, int n_in,
                              void* d_out, int out_size, void* d_ws, size_t ws_size,
                              hipStream_t stream){
  const float* x   = (const float*)d_in[0];
  const int*   eix = (const int*)  d_in[1];
  const float* W0  = (const float*)d_in[2];
  const float* al0 = (const float*)d_in[3];
  const float* ar0 = (const float*)d_in[4];
  const float* b0  = (const float*)d_in[5];
  const float* W1  = (const float*)d_in[6];
  const float* al1 = (const float*)d_in[7];
  const float* ar1 = (const float*)d_in[8];
  const float* b1  = (const float*)d_in[9];
  const float* W2  = (const float*)d_in[10];
  const float* al2 = (const float*)d_in[11];
  const float* ar2 = (const float*)d_in[12];
  const float* b2  = (const float*)d_in[13];
  float* logits = (float*)d_out;

  const int N = in_sizes[0] / 256;   // 50000
  const int E = in_sizes[1] / 2;     // 800000
  const int* src = eix;
  const int* dst = eix + E;
  const int nb = (N + 1023) / 1024;

  char* ws = (char*)d_ws;
  auto alloc = [&](size_t bytes)->char*{
    char* p = ws; ws += (bytes + 255) & ~(size_t)255; return p;
  };
  const int nblocksM = (N + 127)/128;
  const int Mpad = nblocksM * 128;
  const size_t apackElems = (size_t)Mpad * 256;
  int*   counts    = (int*)  alloc((size_t)N*4);
  int*   offsets   = (int*)  alloc((size_t)(N+1)*4);
  int*   cursor    = (int*)  alloc((size_t)N*4);
  int*   blocksums = (int*)  alloc((size_t)nb*4);
  int*   ssrc      = (int*)  alloc((size_t)E*4);
  __hip_bfloat16* bufF = (__hip_bfloat16*)alloc((size_t)N*256*2);   // gemm output (bf16, row-major)
  ushortT* Hh      = (ushortT*)alloc(apackElems*2);                  // A hi plane [t][Mpad][32]
  ushortT* Hl      = (ushortT*)alloc(apackElems*2);                  // A lo plane
  float* el_buf    = (float*)alloc((size_t)N*4*4);
  float* er_buf    = (float*)alloc((size_t)N*4*4);
  ushortT* Wph0 = (ushortT*)alloc(16*8*64*8*2);
  ushortT* Wpl0 = (ushortT*)alloc(16*8*64*8*2);
  ushortT* Wph1 = (ushortT*)alloc(16*8*64*8*2);
  ushortT* Wpl1 = (ushortT*)alloc(16*8*64*8*2);
  ushortT* Wph2 = (ushortT*)alloc(16*8*64*8*2);
  ushortT* Wpl2 = (ushortT*)alloc(16*8*64*8*2);

  // sort edges by dst (graph fixed across layers — one sort per call)
  hipMemsetAsync(counts, 0, (size_t)N*4, stream);
  hist_kernel   <<<(E+255)/256, 256, 0, stream>>>(dst, E, counts);
  scan1_kernel  <<<nb, 1024, 0, stream>>>(counts, N, offsets, blocksums);
  scan2_kernel  <<<1, 64, 0, stream>>>(blocksums, nb);
  scan3_kernel  <<<nb, 1024, 0, stream>>>(offsets, blocksums, N, E, cursor);
  scatter_kernel<<<(E+255)/256, 256, 0, stream>>>(src, dst, E, cursor, ssrc);

  // weight + x packing (fragment order, hi/lo split)
  wsplit_pack<<<32, 256, 0, stream>>>(W0, 256, Wph0, Wpl0);
  wsplit_pack<<<32, 256, 0, stream>>>(W1, 256, Wph1, Wpl1);
  wsplit_pack<<<32, 256, 0, stream>>>(W2, 160, Wph2, Wpl2);
  int xtotal = 8 * Mpad;
  xsplit_pack<<<(xtotal+255)/256, 256, 0, stream>>>(x, N, Mpad, Hh, Hl);

  int ggBlocks = Mpad / 32;        // block = 32 rows x full-N; A read exactly once
  int aggGrid  = (N+3)/4;
  // layer 0 (el/er fused in gemm epilogue; edge weights fused in agg)
  gemm_packed<<<ggBlocks, 256, 0, stream>>>(Hh, Hl, Wph0, Wpl0, (ushortT*)bufF, N, Mpad, 256, al0, ar0, el_buf, er_buf);
  agg_kernel<<<aggGrid, 256, 0, stream>>>((const uint4*)bufF, el_buf, er_buf, offsets, ssrc, b0, Hh, Hl, N, Mpad);
  // layer 1
  gemm_packed<<<ggBlocks, 256, 0, stream>>>(Hh, Hl, Wph1, Wpl1, (ushortT*)bufF, N, Mpad, 256, al1, ar1, el_buf, er_buf);
  agg_kernel<<<aggGrid, 256, 0, stream>>>((const uint4*)bufF, el_buf, er_buf, offsets, ssrc, b1, Hh, Hl, N, Mpad);
  // layer 2 (N=160: waves 2/3 partially idle on zero-padded B cols; stores guarded)
  gemm_packed<<<ggBlocks, 256, 0, stream>>>(Hh, Hl, Wph2, Wpl2, (ushortT*)bufF, N, Mpad, 160, nullptr, nullptr, nullptr, nullptr);
  attn_proj_bf<<<N, 256, 0, stream>>>(bufF, al2, ar2, el_buf, er_buf, 40);
  agg2_kernel<<<aggGrid, 256, 0, stream>>>((const uint2*)bufF, el_buf, er_buf, offsets, ssrc, b2, logits, N);
}